// Round 1
// baseline (398.305 us; speedup 1.0000x reference)
//
#include <hip/hip_runtime.h>
#include <hip/hip_bf16.h>

#define Bb 128
#define LQ 32
#define LD 512
#define Hh 768
#define Cc 128

typedef short bf16x8 __attribute__((ext_vector_type(8)));
typedef float f32x4 __attribute__((ext_vector_type(4)));

__device__ __forceinline__ short f2bf(float f) {
  union { float f; unsigned u; } v;
  v.f = f;
  unsigned u = v.u + (0x7FFFu + ((v.u >> 16) & 1u));  // RNE
  return (short)(u >> 16);
}

// K0: W (H,C) fp32 -> Wt (C,H) bf16 (transposed so B-fragments are contiguous)
__global__ __launch_bounds__(256) void k_wt(const float* __restrict__ W,
                                            short* __restrict__ Wt) {
  int idx = blockIdx.x * 256 + threadIdx.x;  // grid covers H*C exactly
  int h = idx >> 7;   // / 128
  int c = idx & 127;
  Wt[c * Hh + h] = f2bf(W[idx]);
}

// Projection GEMM: Y = X @ W + b_comp, fused mask (+ importance for docs).
// Block = 256 thr = 4 waves; block tile 128 rows; wave tile 32 rows x 128 cols.
// MFMA 16x16x32 bf16. A: fp32 from HBM, converted in-register. B: bf16 from L2.
template <int IS_DOC>
__global__ __launch_bounds__(256) void k_proj(
    const float* __restrict__ X, const short* __restrict__ Wt,
    const float* __restrict__ bcomp, const int* __restrict__ mask,
    const float* __restrict__ wstop, const float* __restrict__ bstop,
    float* __restrict__ Y) {
  const int tid = threadIdx.x;
  const int wave = tid >> 6;
  const int lane = tid & 63;
  const int quad = lane >> 4;
  const int lm = lane & 15;
  const long row0 = (long)blockIdx.x * 128 + wave * 32;

  // A fragment base pointers for the 2 m-tiles: lane reads 8 consecutive k.
  const float* pa0 = X + (row0 + lm) * Hh + quad * 8;
  const float* pa1 = pa0 + 16 * Hh;
  // B fragment base: Wt[n][k], n = j*16+lm, k = kk + quad*8 (.. +8)
  const short* pbb = Wt + lm * Hh + quad * 8;

  f32x4 acc[2][8];
#pragma unroll
  for (int i = 0; i < 2; ++i)
#pragma unroll
    for (int j = 0; j < 8; ++j) acc[i][j] = (f32x4){0.f, 0.f, 0.f, 0.f};

  for (int kk = 0; kk < Hh; kk += 32) {
    float4 a0l = *(const float4*)(pa0 + kk);
    float4 a0h = *(const float4*)(pa0 + kk + 4);
    float4 a1l = *(const float4*)(pa1 + kk);
    float4 a1h = *(const float4*)(pa1 + kk + 4);
    bf16x8 fb[8];
#pragma unroll
    for (int j = 0; j < 8; ++j)
      fb[j] = *(const bf16x8*)(pbb + j * 16 * Hh + kk);
    bf16x8 fa0, fa1;
    fa0[0] = f2bf(a0l.x); fa0[1] = f2bf(a0l.y);
    fa0[2] = f2bf(a0l.z); fa0[3] = f2bf(a0l.w);
    fa0[4] = f2bf(a0h.x); fa0[5] = f2bf(a0h.y);
    fa0[6] = f2bf(a0h.z); fa0[7] = f2bf(a0h.w);
    fa1[0] = f2bf(a1l.x); fa1[1] = f2bf(a1l.y);
    fa1[2] = f2bf(a1l.z); fa1[3] = f2bf(a1l.w);
    fa1[4] = f2bf(a1h.x); fa1[5] = f2bf(a1h.y);
    fa1[6] = f2bf(a1h.z); fa1[7] = f2bf(a1h.w);
#pragma unroll
    for (int j = 0; j < 8; ++j) {
      acc[0][j] = __builtin_amdgcn_mfma_f32_16x16x32_bf16(fa0, fb[j], acc[0][j], 0, 0, 0);
      acc[1][j] = __builtin_amdgcn_mfma_f32_16x16x32_bf16(fa1, fb[j], acc[1][j], 0, 0, 0);
    }
  }

  // Epilogue. C/D layout: col = j*16 + lm, row = i*16 + quad*4 + r.
  float bc[8], ws[8];
#pragma unroll
  for (int j = 0; j < 8; ++j) bc[j] = bcomp[j * 16 + lm];
  if (IS_DOC) {
#pragma unroll
    for (int j = 0; j < 8; ++j) ws[j] = wstop[j * 16 + lm];
  }
  const float bs = IS_DOC ? bstop[0] : 0.f;

#pragma unroll
  for (int i = 0; i < 2; ++i) {
#pragma unroll
    for (int r = 0; r < 4; ++r) {
      const long row = row0 + i * 16 + quad * 4 + r;
      float v[8];
#pragma unroll
      for (int j = 0; j < 8; ++j) v[j] = acc[i][j][r] + bc[j];
      float scale;
      if (IS_DOC) {
        // importance = relu(d_tok . w_stop + b_stop); row spans the 16 lanes
        // of this quad (cols j*16+lm) -> butterfly sum within the quad.
        float p = 0.f;
#pragma unroll
        for (int j = 0; j < 8; ++j) p += v[j] * ws[j];
        p += __shfl_xor(p, 1);
        p += __shfl_xor(p, 2);
        p += __shfl_xor(p, 4);
        p += __shfl_xor(p, 8);
        float imp = fmaxf(p + bs, 0.f);
        scale = imp * (float)mask[row];
      } else {
        scale = (float)mask[row];
      }
      float* yr = Y + row * Cc;
#pragma unroll
      for (int j = 0; j < 8; ++j) yr[j * 16 + lm] = v[j] * scale;
    }
  }
}

// Scores: per (chunk of 64 doc tokens, batch): partial max over k per q row.
__global__ __launch_bounds__(256) void k_scores(
    const float* __restrict__ Qv, const float* __restrict__ Dv,
    const int* __restrict__ dmask, float* __restrict__ partial) {
  const int chunk = blockIdx.x;  // 0..7
  const int b = blockIdx.y;
  const int tid = threadIdx.x;
  __shared__ float lq[LQ][Cc + 4];   // +4 keeps 16B align, breaks conflicts
  __shared__ float ldv[64][Cc + 4];
  __shared__ float pm[LQ][16];
  __shared__ int dmsk[64];

  {
    const float4* src = (const float4*)(Qv + (size_t)b * LQ * Cc);
    for (int i = tid; i < LQ * Cc / 4; i += 256) {
      float4 v = src[i];
      int q = i >> 5;
      int c = (i & 31) << 2;
      *(float4*)&lq[q][c] = v;
    }
  }
  const int k0 = chunk * 64;
  {
    const float4* src = (const float4*)(Dv + ((size_t)b * LD + k0) * Cc);
    for (int i = tid; i < 64 * Cc / 4; i += 256) {
      float4 v = src[i];
      int k = i >> 5;
      int c = (i & 31) << 2;
      *(float4*)&ldv[k][c] = v;
    }
  }
  if (tid < 64) dmsk[tid] = dmask[(size_t)b * LD + k0 + tid];
  __syncthreads();

  const int qt = tid & 15;   // q rows qt and qt+16 (stride-16 avoids bank conflict)
  const int kt = tid >> 4;   // 4 doc tokens kt*4..+3
  const int kbase = kt * 4;
  float a[2][4];
#pragma unroll
  for (int qi = 0; qi < 2; ++qi)
#pragma unroll
    for (int ki = 0; ki < 4; ++ki) a[qi][ki] = 0.f;

  for (int c = 0; c < Cc; c += 4) {
    float4 q0 = *(float4*)&lq[qt][c];
    float4 q1 = *(float4*)&lq[qt + 16][c];
    float4 d0 = *(float4*)&ldv[kbase + 0][c];
    float4 d1 = *(float4*)&ldv[kbase + 1][c];
    float4 d2 = *(float4*)&ldv[kbase + 2][c];
    float4 d3 = *(float4*)&ldv[kbase + 3][c];
    a[0][0] += q0.x * d0.x + q0.y * d0.y + q0.z * d0.z + q0.w * d0.w;
    a[0][1] += q0.x * d1.x + q0.y * d1.y + q0.z * d1.z + q0.w * d1.w;
    a[0][2] += q0.x * d2.x + q0.y * d2.y + q0.z * d2.z + q0.w * d2.w;
    a[0][3] += q0.x * d3.x + q0.y * d3.y + q0.z * d3.z + q0.w * d3.w;
    a[1][0] += q1.x * d0.x + q1.y * d0.y + q1.z * d0.z + q1.w * d0.w;
    a[1][1] += q1.x * d1.x + q1.y * d1.y + q1.z * d1.z + q1.w * d1.w;
    a[1][2] += q1.x * d2.x + q1.y * d2.y + q1.z * d2.z + q1.w * d2.w;
    a[1][3] += q1.x * d3.x + q1.y * d3.y + q1.z * d3.z + q1.w * d3.w;
  }
  float m0 = -1000.f, m1 = -1000.f;
#pragma unroll
  for (int ki = 0; ki < 4; ++ki) {
    if (dmsk[kbase + ki]) {
      m0 = fmaxf(m0, a[0][ki]);
      m1 = fmaxf(m1, a[1][ki]);
    }
  }
  pm[qt][kt] = m0;
  pm[qt + 16][kt] = m1;
  __syncthreads();
  if (tid < LQ) {
    float mx = pm[tid][0];
#pragma unroll
    for (int t = 1; t < 16; ++t) mx = fmaxf(mx, pm[tid][t]);
    partial[((size_t)b * LQ + tid) * 8 + chunk] = mx;
  }
}

// Finalize: cls dot on raw CLS vectors, max over chunks, masked sum, merge.
__global__ __launch_bounds__(256) void k_final(
    const float* __restrict__ qh, const float* __restrict__ dh,
    const int* __restrict__ qmask, const float* __restrict__ partial,
    const float* __restrict__ merger, float* __restrict__ out) {
  const int b = blockIdx.x;
  const int tid = threadIdx.x;
  __shared__ float red[256];
  __shared__ float clss;
  const float* qc = qh + (size_t)b * LQ * Hh;  // q row 0 = CLS
  const float* dc = dh + (size_t)b * LD * Hh;  // d row 0 = CLS
  float s = 0.f;
  for (int h = tid; h < Hh; h += 256) s += qc[h] * dc[h];
  red[tid] = s;
  __syncthreads();
  for (int off = 128; off > 0; off >>= 1) {
    if (tid < off) red[tid] += red[tid + off];
    __syncthreads();
  }
  if (tid == 0) clss = red[0];
  __syncthreads();
  float t = 0.f;
  if (tid < LQ) {
    const float* pp = partial + ((size_t)b * LQ + tid) * 8;
    float mx = pp[0];
#pragma unroll
    for (int c = 1; c < 8; ++c) mx = fmaxf(mx, pp[c]);
    if (qmask[b * LQ + tid]) t = mx;
  }
  red[tid] = t;
  __syncthreads();
  for (int off = 128; off > 0; off >>= 1) {
    if (tid < off) red[tid] += red[tid + off];
    __syncthreads();
  }
  if (tid == 0) {
    float w = 1.f / (1.f + expf(-merger[0]));
    float cs = clss * w;
    float ts = red[0] * (1.f - w);
    out[b] = cs + ts;        // score
    out[Bb + b] = cs;        // cls_score
    out[2 * Bb + b] = ts;    // term_score
  }
}

extern "C" void kernel_launch(void* const* d_in, const int* in_sizes, int n_in,
                              void* d_out, int out_size, void* d_ws, size_t ws_size,
                              hipStream_t stream) {
  const float* qh  = (const float*)d_in[0];  // (B,LQ,H)
  const float* dh  = (const float*)d_in[1];  // (B,LD,H)
  const int*   qm  = (const int*)d_in[2];    // (B,LQ)
  const int*   dm  = (const int*)d_in[3];    // (B,LD)
  const float* W   = (const float*)d_in[4];  // (H,C)
  const float* bc  = (const float*)d_in[5];  // (C)
  const float* wst = (const float*)d_in[6];  // (C,1)
  const float* bst = (const float*)d_in[7];  // (1)
  const float* mrg = (const float*)d_in[8];  // (1)
  float* out = (float*)d_out;                // 3*B floats

  char* ws = (char*)d_ws;
  short* Wt  = (short*)ws;                                  // 192 KB bf16 W^T
  float* qv  = (float*)(ws + 196608);                       // 2 MB q_vecs
  float* dv  = (float*)(ws + 196608 + 2097152);             // 32 MB d_vecs
  float* prt = (float*)(ws + 196608 + 2097152 + 33554432);  // 128 KB partial max

  k_wt<<<(Hh * Cc) / 256, 256, 0, stream>>>(W, Wt);
  k_proj<0><<<(Bb * LQ) / 128, 256, 0, stream>>>(qh, Wt, bc, qm, nullptr, nullptr, qv);
  k_proj<1><<<(Bb * LD) / 128, 256, 0, stream>>>(dh, Wt, bc, dm, wst, bst, dv);
  k_scores<<<dim3(8, Bb), 256, 0, stream>>>(qv, dv, dm, prt);
  k_final<<<Bb, 256, 0, stream>>>(qh, dh, qm, prt, mrg, out);
}

// Round 2
// 395.751 us; speedup vs baseline: 1.0065x; 1.0065x over previous
//
#include <hip/hip_runtime.h>
#include <hip/hip_bf16.h>

#define Bb 128
#define LQ 32
#define LD 512
#define Hh 768
#define Cc 128

#define QBLOCKS ((Bb * LQ) / 64)   // 64 query blocks (64 rows each)
#define DBLOCKS ((Bb * LD) / 64)   // 1024 doc blocks

typedef short bf16x8 __attribute__((ext_vector_type(8)));
typedef float f32x4 __attribute__((ext_vector_type(4)));

__device__ __forceinline__ short f2bf(float f) {
  union { float f; unsigned u; } v;
  v.f = f;
  unsigned u = v.u + (0x7FFFu + ((v.u >> 16) & 1u));  // RNE
  return (short)(u >> 16);
}

__device__ __forceinline__ void pack8(bf16x8& d, const float4& lo, const float4& hi) {
  d[0] = f2bf(lo.x); d[1] = f2bf(lo.y); d[2] = f2bf(lo.z); d[3] = f2bf(lo.w);
  d[4] = f2bf(hi.x); d[5] = f2bf(hi.y); d[6] = f2bf(hi.z); d[7] = f2bf(hi.w);
}

// K0: W (H,C) fp32 -> Wt (C,H) bf16 (transposed so B-fragments are contiguous)
__global__ __launch_bounds__(256) void k_wt(const float* __restrict__ W,
                                            short* __restrict__ Wt) {
  int idx = blockIdx.x * 256 + threadIdx.x;  // grid covers H*C exactly
  int h = idx >> 7;   // / 128
  int c = idx & 127;
  Wt[c * Hh + h] = f2bf(W[idx]);
}

// Merged projection GEMM for query+doc: Y = X @ W + b_comp, fused mask
// (+ importance relu-dot for docs). Block = 256 thr = 4 waves; block tile
// 64 rows; wave tile 16 rows x 128 cols (8 n-tiles of mfma_f32_16x16x32_bf16).
// Software pipeline: prefetch next 64-k A-chunk while computing current.
// Blocks [0, DBLOCKS) = doc rows, [DBLOCKS, DBLOCKS+QBLOCKS) = query rows.
__global__ __launch_bounds__(256) void k_proj_all(
    const float* __restrict__ qh, const float* __restrict__ dh,
    const short* __restrict__ Wt, const float* __restrict__ bcomp,
    const int* __restrict__ qmask, const int* __restrict__ dmask,
    const float* __restrict__ wstop, const float* __restrict__ bstop,
    float* __restrict__ qv, float* __restrict__ dv) {
  const int tid = threadIdx.x;
  const int wave = tid >> 6;
  const int lane = tid & 63;
  const int quad = lane >> 4;
  const int lm = lane & 15;

  const int blk = blockIdx.x;
  const bool is_doc = blk < DBLOCKS;
  const float* X;
  float* Y;
  const int* mask;
  long row0;
  if (is_doc) {
    X = dh; Y = dv; mask = dmask;
    row0 = (long)blk * 64 + wave * 16;
  } else {
    X = qh; Y = qv; mask = qmask;
    row0 = (long)(blk - DBLOCKS) * 64 + wave * 16;
  }

  // A fragment: lane reads row row0+lm, cols quad*8 + [0,8) within each chunk.
  const float* pa = X + (row0 + lm) * (long)Hh + quad * 8;
  // B fragment: Wt[n][k], n = j*16+lm, k = quad*8 + [0,8) within each chunk.
  const short* pb = Wt + lm * Hh + quad * 8;

  f32x4 acc[8];
#pragma unroll
  for (int j = 0; j < 8; ++j) acc[j] = (f32x4){0.f, 0.f, 0.f, 0.f};

  // prime the pipeline: first 64-k chunk (two 32-k MFMA chunks)
  float4 c0 = *(const float4*)(pa);
  float4 c1 = *(const float4*)(pa + 4);
  float4 c2 = *(const float4*)(pa + 32);
  float4 c3 = *(const float4*)(pa + 36);

  for (int kk = 0; kk < Hh; kk += 64) {
    int kn = kk + 64;
    if (kn >= Hh) kn = 0;  // harmless re-read of chunk 0 on the last iter
    float4 n0 = *(const float4*)(pa + kn);
    float4 n1 = *(const float4*)(pa + kn + 4);
    float4 n2 = *(const float4*)(pa + kn + 32);
    float4 n3 = *(const float4*)(pa + kn + 36);

    bf16x8 fa;
    pack8(fa, c0, c1);
#pragma unroll
    for (int j = 0; j < 8; ++j) {
      bf16x8 fb = *(const bf16x8*)(pb + j * 16 * Hh + kk);
      acc[j] = __builtin_amdgcn_mfma_f32_16x16x32_bf16(fa, fb, acc[j], 0, 0, 0);
    }
    pack8(fa, c2, c3);
#pragma unroll
    for (int j = 0; j < 8; ++j) {
      bf16x8 fb = *(const bf16x8*)(pb + j * 16 * Hh + kk + 32);
      acc[j] = __builtin_amdgcn_mfma_f32_16x16x32_bf16(fa, fb, acc[j], 0, 0, 0);
    }
    c0 = n0; c1 = n1; c2 = n2; c3 = n3;
  }

  // Epilogue. C/D layout: col = j*16 + lm, row = quad*4 + r.
  float bc[8], wsv[8];
#pragma unroll
  for (int j = 0; j < 8; ++j) bc[j] = bcomp[j * 16 + lm];
  if (is_doc) {
#pragma unroll
    for (int j = 0; j < 8; ++j) wsv[j] = wstop[j * 16 + lm];
  }
  const float bs = is_doc ? bstop[0] : 0.f;

#pragma unroll
  for (int r = 0; r < 4; ++r) {
    const long row = row0 + quad * 4 + r;
    float v[8];
#pragma unroll
    for (int j = 0; j < 8; ++j) v[j] = acc[j][r] + bc[j];
    float scale;
    if (is_doc) {
      // importance = relu(d_tok . w_stop + b_stop); the row's 128 cols live
      // on the 16 lanes of this quad -> butterfly sum within the quad.
      float p = 0.f;
#pragma unroll
      for (int j = 0; j < 8; ++j) p += v[j] * wsv[j];
      p += __shfl_xor(p, 1);
      p += __shfl_xor(p, 2);
      p += __shfl_xor(p, 4);
      p += __shfl_xor(p, 8);
      float imp = fmaxf(p + bs, 0.f);
      scale = imp * (float)mask[row];
    } else {
      scale = (float)mask[row];
    }
    float* yr = Y + row * Cc;
#pragma unroll
    for (int j = 0; j < 8; ++j) yr[j * 16 + lm] = v[j] * scale;
  }
}

// Scores: per (chunk of 64 doc tokens, batch): partial max over k per q row.
__global__ __launch_bounds__(256) void k_scores(
    const float* __restrict__ Qv, const float* __restrict__ Dv,
    const int* __restrict__ dmask, float* __restrict__ partial) {
  const int chunk = blockIdx.x;  // 0..7
  const int b = blockIdx.y;
  const int tid = threadIdx.x;
  __shared__ float lq[LQ][Cc + 4];   // +4 keeps 16B align, breaks conflicts
  __shared__ float ldv[64][Cc + 4];
  __shared__ float pm[LQ][16];
  __shared__ int dmsk[64];

  {
    const float4* src = (const float4*)(Qv + (size_t)b * LQ * Cc);
    for (int i = tid; i < LQ * Cc / 4; i += 256) {
      float4 v = src[i];
      int q = i >> 5;
      int c = (i & 31) << 2;
      *(float4*)&lq[q][c] = v;
    }
  }
  const int k0 = chunk * 64;
  {
    const float4* src = (const float4*)(Dv + ((size_t)b * LD + k0) * Cc);
    for (int i = tid; i < 64 * Cc / 4; i += 256) {
      float4 v = src[i];
      int k = i >> 5;
      int c = (i & 31) << 2;
      *(float4*)&ldv[k][c] = v;
    }
  }
  if (tid < 64) dmsk[tid] = dmask[(size_t)b * LD + k0 + tid];
  __syncthreads();

  const int qt = tid & 15;   // q rows qt and qt+16
  const int kt = tid >> 4;   // 4 doc tokens kt*4..+3
  const int kbase = kt * 4;
  float a[2][4];
#pragma unroll
  for (int qi = 0; qi < 2; ++qi)
#pragma unroll
    for (int ki = 0; ki < 4; ++ki) a[qi][ki] = 0.f;

  for (int c = 0; c < Cc; c += 4) {
    float4 q0 = *(float4*)&lq[qt][c];
    float4 q1 = *(float4*)&lq[qt + 16][c];
    float4 d0 = *(float4*)&ldv[kbase + 0][c];
    float4 d1 = *(float4*)&ldv[kbase + 1][c];
    float4 d2 = *(float4*)&ldv[kbase + 2][c];
    float4 d3 = *(float4*)&ldv[kbase + 3][c];
    a[0][0] += q0.x * d0.x + q0.y * d0.y + q0.z * d0.z + q0.w * d0.w;
    a[0][1] += q0.x * d1.x + q0.y * d1.y + q0.z * d1.z + q0.w * d1.w;
    a[0][2] += q0.x * d2.x + q0.y * d2.y + q0.z * d2.z + q0.w * d2.w;
    a[0][3] += q0.x * d3.x + q0.y * d3.y + q0.z * d3.z + q0.w * d3.w;
    a[1][0] += q1.x * d0.x + q1.y * d0.y + q1.z * d0.z + q1.w * d0.w;
    a[1][1] += q1.x * d1.x + q1.y * d1.y + q1.z * d1.z + q1.w * d1.w;
    a[1][2] += q1.x * d2.x + q1.y * d2.y + q1.z * d2.z + q1.w * d2.w;
    a[1][3] += q1.x * d3.x + q1.y * d3.y + q1.z * d3.z + q1.w * d3.w;
  }
  float m0 = -1000.f, m1 = -1000.f;
#pragma unroll
  for (int ki = 0; ki < 4; ++ki) {
    if (dmsk[kbase + ki]) {
      m0 = fmaxf(m0, a[0][ki]);
      m1 = fmaxf(m1, a[1][ki]);
    }
  }
  pm[qt][kt] = m0;
  pm[qt + 16][kt] = m1;
  __syncthreads();
  if (tid < LQ) {
    float mx = pm[tid][0];
#pragma unroll
    for (int t = 1; t < 16; ++t) mx = fmaxf(mx, pm[tid][t]);
    partial[((size_t)b * LQ + tid) * 8 + chunk] = mx;
  }
}

// Finalize: cls dot on raw CLS vectors, max over chunks, masked sum, merge.
__global__ __launch_bounds__(256) void k_final(
    const float* __restrict__ qh, const float* __restrict__ dh,
    const int* __restrict__ qmask, const float* __restrict__ partial,
    const float* __restrict__ merger, float* __restrict__ out) {
  const int b = blockIdx.x;
  const int tid = threadIdx.x;
  __shared__ float red[256];
  __shared__ float clss;
  const float* qc = qh + (size_t)b * LQ * Hh;  // q row 0 = CLS
  const float* dc = dh + (size_t)b * LD * Hh;  // d row 0 = CLS
  float s = 0.f;
  for (int h = tid; h < Hh; h += 256) s += qc[h] * dc[h];
  red[tid] = s;
  __syncthreads();
  for (int off = 128; off > 0; off >>= 1) {
    if (tid < off) red[tid] += red[tid + off];
    __syncthreads();
  }
  if (tid == 0) clss = red[0];
  __syncthreads();
  float t = 0.f;
  if (tid < LQ) {
    const float* pp = partial + ((size_t)b * LQ + tid) * 8;
    float mx = pp[0];
#pragma unroll
    for (int c = 1; c < 8; ++c) mx = fmaxf(mx, pp[c]);
    if (qmask[b * LQ + tid]) t = mx;
  }
  red[tid] = t;
  __syncthreads();
  for (int off = 128; off > 0; off >>= 1) {
    if (tid < off) red[tid] += red[tid + off];
    __syncthreads();
  }
  if (tid == 0) {
    float w = 1.f / (1.f + expf(-merger[0]));
    float cs = clss * w;
    float ts = red[0] * (1.f - w);
    out[b] = cs + ts;        // score
    out[Bb + b] = cs;        // cls_score
    out[2 * Bb + b] = ts;    // term_score
  }
}

extern "C" void kernel_launch(void* const* d_in, const int* in_sizes, int n_in,
                              void* d_out, int out_size, void* d_ws, size_t ws_size,
                              hipStream_t stream) {
  const float* qh  = (const float*)d_in[0];  // (B,LQ,H)
  const float* dh  = (const float*)d_in[1];  // (B,LD,H)
  const int*   qm  = (const int*)d_in[2];    // (B,LQ)
  const int*   dm  = (const int*)d_in[3];    // (B,LD)
  const float* W   = (const float*)d_in[4];  // (H,C)
  const float* bc  = (const float*)d_in[5];  // (C)
  const float* wst = (const float*)d_in[6];  // (C,1)
  const float* bst = (const float*)d_in[7];  // (1)
  const float* mrg = (const float*)d_in[8];  // (1)
  float* out = (float*)d_out;                // 3*B floats

  char* ws = (char*)d_ws;
  short* Wt  = (short*)ws;                                  // 192 KB bf16 W^T
  float* qv  = (float*)(ws + 196608);                       // 2 MB q_vecs
  float* dv  = (float*)(ws + 196608 + 2097152);             // 32 MB d_vecs
  float* prt = (float*)(ws + 196608 + 2097152 + 33554432);  // 128 KB partial max

  k_wt<<<(Hh * Cc) / 256, 256, 0, stream>>>(W, Wt);
  k_proj_all<<<DBLOCKS + QBLOCKS, 256, 0, stream>>>(qh, dh, Wt, bc, qm, dm,
                                                    wst, bst, qv, dv);
  k_scores<<<dim3(8, Bb), 256, 0, stream>>>(qv, dv, dm, prt);
  k_final<<<Bb, 256, 0, stream>>>(qh, dh, qm, prt, mrg, out);
}

// Round 3
// 345.940 us; speedup vs baseline: 1.1514x; 1.1440x over previous
//
#include <hip/hip_runtime.h>
#include <hip/hip_bf16.h>

#define Bb 128
#define LQ 32
#define LD 512
#define Hh 768
#define Cc 128

#define QBLOCKS ((Bb * LQ) / 64)   // 64 query blocks (64 rows each)
#define DBLOCKS ((Bb * LD) / 64)   // 1024 doc blocks

typedef short bf16x8 __attribute__((ext_vector_type(8)));
typedef float f32x4 __attribute__((ext_vector_type(4)));

__device__ __forceinline__ short f2bf(float f) {
  union { float f; unsigned u; } v;
  v.f = f;
  unsigned u = v.u + (0x7FFFu + ((v.u >> 16) & 1u));  // RNE
  return (short)(u >> 16);
}

__device__ __forceinline__ void pack8(bf16x8& d, const float4& lo, const float4& hi) {
  d[0] = f2bf(lo.x); d[1] = f2bf(lo.y); d[2] = f2bf(lo.z); d[3] = f2bf(lo.w);
  d[4] = f2bf(hi.x); d[5] = f2bf(hi.y); d[6] = f2bf(hi.z); d[7] = f2bf(hi.w);
}

// Async global->LDS, 16B per lane. Dest is wave-uniform base + lane*16.
__device__ __forceinline__ void gload16(const void* g, void* l) {
  __builtin_amdgcn_global_load_lds(
      (const __attribute__((address_space(1))) void*)g,
      (__attribute__((address_space(3))) void*)l, 16, 0, 0);
}

// K0: W (H,C) fp32 -> Wt (C,H) bf16 (transposed so B-chunks are row-contiguous)
__global__ __launch_bounds__(256) void k_wt(const float* __restrict__ W,
                                            short* __restrict__ Wt) {
  int idx = blockIdx.x * 256 + threadIdx.x;  // grid covers H*C exactly
  int h = idx >> 7;   // / 128
  int c = idx & 127;
  Wt[c * Hh + h] = f2bf(W[idx]);
}

// Merged projection GEMM (query+doc): Y = X @ W + b_comp, fused mask
// (+ importance relu-dot for docs). Block = 256 thr = 4 waves, 64-row tile,
// full 128 cols. K-loop: BK=64, both A (fp32) and B (bf16) staged to LDS via
// global_load_lds w/ XOR-swizzled 16B granules (slot = granule ^ (row&7)) so
// fragment ds_read_b128s are bank-uniform. Wave tile 16 rows x 128 cols.
__global__ __launch_bounds__(256) void k_proj_all(
    const float* __restrict__ qh, const float* __restrict__ dh,
    const short* __restrict__ Wt, const float* __restrict__ bcomp,
    const int* __restrict__ qmask, const int* __restrict__ dmask,
    const float* __restrict__ wstop, const float* __restrict__ bstop,
    float* __restrict__ qv, float* __restrict__ dv) {
  __shared__ float lA[64 * 64];    // [r][slot(4 floats)] 16 KB
  __shared__ short lB[128 * 64];   // [n][slot(8 shorts)] 16 KB

  const int tid = threadIdx.x;
  const int wave = tid >> 6;
  const int lane = tid & 63;
  const int quad = lane >> 4;
  const int lm = lane & 15;

  const int blk = blockIdx.x;
  const bool is_doc = blk < DBLOCKS;
  const float* X;
  float* Y;
  const int* mask;
  long row0b;
  if (is_doc) {
    X = dh; Y = dv; mask = dmask;
    row0b = (long)blk * 64;
  } else {
    X = qh; Y = qv; mask = qmask;
    row0b = (long)(blk - DBLOCKS) * 64;
  }

  f32x4 acc[8];
#pragma unroll
  for (int j = 0; j < 8; ++j) acc[j] = (f32x4){0.f, 0.f, 0.f, 0.f};

  // Per-lane staging indices (invariant across kk).
  // A: u in [0,1024): r=u>>4 (64 rows), s=u&15 (16 granules of 4 floats)
  // B: u in [0,1024): n=u>>3 (128 cols), s=u&7  (8 granules of 8 shorts)
  const int ubase = wave * 256 + lane;

  for (int kk = 0; kk < Hh; kk += 64) {
    // stage A (4 calls x 1KB per wave)
#pragma unroll
    for (int i = 0; i < 4; ++i) {
      int u = ubase + i * 64;
      int r = u >> 4, s = u & 15;
      int g = s ^ (r & 7);
      gload16(X + (row0b + r) * (long)Hh + kk + g * 4,
              &lA[(wave * 4 + i) * 256]);
    }
    // stage B (4 calls x 1KB per wave)
#pragma unroll
    for (int i = 0; i < 4; ++i) {
      int u = ubase + i * 64;
      int n = u >> 3, s = u & 7;
      int g = s ^ (n & 7);
      gload16(Wt + n * Hh + kk + g * 8,
              &lB[(wave * 4 + i) * 512]);
    }
    __syncthreads();

    const int rr = wave * 16 + lm;
#pragma unroll
    for (int h = 0; h < 2; ++h) {
      const int gf = h * 8 + quad * 2;
      const int s0 = gf ^ (lm & 7);
      const int s1 = (gf + 1) ^ (lm & 7);
      float4 a0 = *(const float4*)&lA[rr * 64 + s0 * 4];
      float4 a1 = *(const float4*)&lA[rr * 64 + s1 * 4];
      bf16x8 fa;
      pack8(fa, a0, a1);
      const int sb = (h * 4 + quad) ^ (lm & 7);
#pragma unroll
      for (int j = 0; j < 8; ++j) {
        bf16x8 fb = *(const bf16x8*)&lB[(j * 16 + lm) * 64 + sb * 8];
        acc[j] = __builtin_amdgcn_mfma_f32_16x16x32_bf16(fa, fb, acc[j], 0, 0, 0);
      }
    }
    __syncthreads();
  }

  // Epilogue. C/D layout: col = j*16 + lm, row = quad*4 + r (within wave tile).
  const long row0 = row0b + wave * 16;
  float bc[8], wsv[8];
#pragma unroll
  for (int j = 0; j < 8; ++j) bc[j] = bcomp[j * 16 + lm];
  if (is_doc) {
#pragma unroll
    for (int j = 0; j < 8; ++j) wsv[j] = wstop[j * 16 + lm];
  }
  const float bs = is_doc ? bstop[0] : 0.f;

#pragma unroll
  for (int r = 0; r < 4; ++r) {
    const long row = row0 + quad * 4 + r;
    float v[8];
#pragma unroll
    for (int j = 0; j < 8; ++j) v[j] = acc[j][r] + bc[j];
    float scale;
    if (is_doc) {
      // importance = relu(d_tok . w_stop + b_stop); the row's 128 cols live
      // on the 16 lanes of this quad -> butterfly sum within the quad.
      float p = 0.f;
#pragma unroll
      for (int j = 0; j < 8; ++j) p += v[j] * wsv[j];
      p += __shfl_xor(p, 1);
      p += __shfl_xor(p, 2);
      p += __shfl_xor(p, 4);
      p += __shfl_xor(p, 8);
      float imp = fmaxf(p + bs, 0.f);
      scale = imp * (float)mask[row];
    } else {
      scale = (float)mask[row];
    }
    float* yr = Y + row * Cc;
#pragma unroll
    for (int j = 0; j < 8; ++j) yr[j * 16 + lm] = v[j] * scale;
  }
}

// Scores: per (chunk of 64 doc tokens, batch): partial max over k per q row.
__global__ __launch_bounds__(256) void k_scores(
    const float* __restrict__ Qv, const float* __restrict__ Dv,
    const int* __restrict__ dmask, float* __restrict__ partial) {
  const int chunk = blockIdx.x;  // 0..7
  const int b = blockIdx.y;
  const int tid = threadIdx.x;
  __shared__ float lq[LQ][Cc + 4];   // +4 keeps 16B align, breaks conflicts
  __shared__ float ldv[64][Cc + 4];
  __shared__ float pm[LQ][16];
  __shared__ int dmsk[64];

  {
    const float4* src = (const float4*)(Qv + (size_t)b * LQ * Cc);
    for (int i = tid; i < LQ * Cc / 4; i += 256) {
      float4 v = src[i];
      int q = i >> 5;
      int c = (i & 31) << 2;
      *(float4*)&lq[q][c] = v;
    }
  }
  const int k0 = chunk * 64;
  {
    const float4* src = (const float4*)(Dv + ((size_t)b * LD + k0) * Cc);
    for (int i = tid; i < 64 * Cc / 4; i += 256) {
      float4 v = src[i];
      int k = i >> 5;
      int c = (i & 31) << 2;
      *(float4*)&ldv[k][c] = v;
    }
  }
  if (tid < 64) dmsk[tid] = dmask[(size_t)b * LD + k0 + tid];
  __syncthreads();

  const int qt = tid & 15;   // q rows qt and qt+16
  const int kt = tid >> 4;   // 4 doc tokens kt*4..+3
  const int kbase = kt * 4;
  float a[2][4];
#pragma unroll
  for (int qi = 0; qi < 2; ++qi)
#pragma unroll
    for (int ki = 0; ki < 4; ++ki) a[qi][ki] = 0.f;

  for (int c = 0; c < Cc; c += 4) {
    float4 q0 = *(float4*)&lq[qt][c];
    float4 q1 = *(float4*)&lq[qt + 16][c];
    float4 d0 = *(float4*)&ldv[kbase + 0][c];
    float4 d1 = *(float4*)&ldv[kbase + 1][c];
    float4 d2 = *(float4*)&ldv[kbase + 2][c];
    float4 d3 = *(float4*)&ldv[kbase + 3][c];
    a[0][0] += q0.x * d0.x + q0.y * d0.y + q0.z * d0.z + q0.w * d0.w;
    a[0][1] += q0.x * d1.x + q0.y * d1.y + q0.z * d1.z + q0.w * d1.w;
    a[0][2] += q0.x * d2.x + q0.y * d2.y + q0.z * d2.z + q0.w * d2.w;
    a[0][3] += q0.x * d3.x + q0.y * d3.y + q0.z * d3.z + q0.w * d3.w;
    a[1][0] += q1.x * d0.x + q1.y * d0.y + q1.z * d0.z + q1.w * d0.w;
    a[1][1] += q1.x * d1.x + q1.y * d1.y + q1.z * d1.z + q1.w * d1.w;
    a[1][2] += q1.x * d2.x + q1.y * d2.y + q1.z * d2.z + q1.w * d2.w;
    a[1][3] += q1.x * d3.x + q1.y * d3.y + q1.z * d3.z + q1.w * d3.w;
  }
  float m0 = -1000.f, m1 = -1000.f;
#pragma unroll
  for (int ki = 0; ki < 4; ++ki) {
    if (dmsk[kbase + ki]) {
      m0 = fmaxf(m0, a[0][ki]);
      m1 = fmaxf(m1, a[1][ki]);
    }
  }
  pm[qt][kt] = m0;
  pm[qt + 16][kt] = m1;
  __syncthreads();
  if (tid < LQ) {
    float mx = pm[tid][0];
#pragma unroll
    for (int t = 1; t < 16; ++t) mx = fmaxf(mx, pm[tid][t]);
    partial[((size_t)b * LQ + tid) * 8 + chunk] = mx;
  }
}

// Finalize: cls dot on raw CLS vectors, max over chunks, masked sum, merge.
__global__ __launch_bounds__(256) void k_final(
    const float* __restrict__ qh, const float* __restrict__ dh,
    const int* __restrict__ qmask, const float* __restrict__ partial,
    const float* __restrict__ merger, float* __restrict__ out) {
  const int b = blockIdx.x;
  const int tid = threadIdx.x;
  __shared__ float red[256];
  __shared__ float clss;
  const float* qc = qh + (size_t)b * LQ * Hh;  // q row 0 = CLS
  const float* dc = dh + (size_t)b * LD * Hh;  // d row 0 = CLS
  float s = 0.f;
  for (int h = tid; h < Hh; h += 256) s += qc[h] * dc[h];
  red[tid] = s;
  __syncthreads();
  for (int off = 128; off > 0; off >>= 1) {
    if (tid < off) red[tid] += red[tid + off];
    __syncthreads();
  }
  if (tid == 0) clss = red[0];
  __syncthreads();
  float t = 0.f;
  if (tid < LQ) {
    const float* pp = partial + ((size_t)b * LQ + tid) * 8;
    float mx = pp[0];
#pragma unroll
    for (int c = 1; c < 8; ++c) mx = fmaxf(mx, pp[c]);
    if (qmask[b * LQ + tid]) t = mx;
  }
  red[tid] = t;
  __syncthreads();
  for (int off = 128; off > 0; off >>= 1) {
    if (tid < off) red[tid] += red[tid + off];
    __syncthreads();
  }
  if (tid == 0) {
    float w = 1.f / (1.f + expf(-merger[0]));
    float cs = clss * w;
    float ts = red[0] * (1.f - w);
    out[b] = cs + ts;        // score
    out[Bb + b] = cs;        // cls_score
    out[2 * Bb + b] = ts;    // term_score
  }
}

extern "C" void kernel_launch(void* const* d_in, const int* in_sizes, int n_in,
                              void* d_out, int out_size, void* d_ws, size_t ws_size,
                              hipStream_t stream) {
  const float* qh  = (const float*)d_in[0];  // (B,LQ,H)
  const float* dh  = (const float*)d_in[1];  // (B,LD,H)
  const int*   qm  = (const int*)d_in[2];    // (B,LQ)
  const int*   dm  = (const int*)d_in[3];    // (B,LD)
  const float* W   = (const float*)d_in[4];  // (H,C)
  const float* bc  = (const float*)d_in[5];  // (C)
  const float* wst = (const float*)d_in[6];  // (C,1)
  const float* bst = (const float*)d_in[7];  // (1)
  const float* mrg = (const float*)d_in[8];  // (1)
  float* out = (float*)d_out;                // 3*B floats

  char* ws = (char*)d_ws;
  short* Wt  = (short*)ws;                                  // 192 KB bf16 W^T
  float* qv  = (float*)(ws + 196608);                       // 2 MB q_vecs
  float* dv  = (float*)(ws + 196608 + 2097152);             // 32 MB d_vecs
  float* prt = (float*)(ws + 196608 + 2097152 + 33554432);  // 128 KB partial max

  k_wt<<<(Hh * Cc) / 256, 256, 0, stream>>>(W, Wt);
  k_proj_all<<<DBLOCKS + QBLOCKS, 256, 0, stream>>>(qh, dh, Wt, bc, qm, dm,
                                                    wst, bst, qv, dv);
  k_scores<<<dim3(8, Bb), 256, 0, stream>>>(qv, dv, dm, prt);
  k_final<<<Bb, 256, 0, stream>>>(qh, dh, qm, prt, mrg, out);
}

// Round 4
// 343.693 us; speedup vs baseline: 1.1589x; 1.0065x over previous
//
#include <hip/hip_runtime.h>
#include <hip/hip_bf16.h>

#define Bb 128
#define LQ 32
#define LD 512
#define Hh 768
#define Cc 128

#define DBLOCKS ((Bb * LD) / 128)  // 512 doc blocks (128 rows each)
#define QBLOCKS ((Bb * LQ) / 128)  // 32 query blocks

typedef short bf16x8 __attribute__((ext_vector_type(8)));
typedef short bf16x4 __attribute__((ext_vector_type(4)));
typedef float f32x4 __attribute__((ext_vector_type(4)));

__device__ __forceinline__ short f2bf(float f) {
  union { float f; unsigned u; } v;
  v.f = f;
  unsigned u = v.u + (0x7FFFu + ((v.u >> 16) & 1u));  // RNE
  return (short)(u >> 16);
}

// K0: W (H,C) fp32 -> Wt (C,H) bf16 (transposed so B-chunks are row-contiguous)
__global__ __launch_bounds__(256) void k_wt(const float* __restrict__ W,
                                            short* __restrict__ Wt) {
  int idx = blockIdx.x * 256 + threadIdx.x;  // grid covers H*C exactly
  int h = idx >> 7;   // / 128
  int c = idx & 127;
  Wt[c * Hh + h] = f2bf(W[idx]);
}

// Merged projection GEMM (query+doc): Y = X @ W + b_comp, fused mask
// (+ importance relu-dot for docs).
// 512 thr = 8 waves; block tile 128 rows x 128 cols; BK=64.
// Global loads are strictly lane-monotone 1KB/instruction (fp32 A from HBM,
// bf16 B from L2) into registers; A packed to bf16 in-register; stored to
// padded LDS (A row stride 144 B, B row stride 160 B -> uniform bank spread
// for both writes and fragment reads). LDS double-buffered, ONE barrier per
// chunk; next-chunk global loads issued before compute for overlap.
__global__ __launch_bounds__(512) void k_proj_all(
    const float* __restrict__ qh, const float* __restrict__ dh,
    const short* __restrict__ Wt, const float* __restrict__ bcomp,
    const int* __restrict__ qmask, const int* __restrict__ dmask,
    const float* __restrict__ wstop, const float* __restrict__ bstop,
    float* __restrict__ qv, float* __restrict__ dv) {
  constexpr int ASTR = 144;          // 64 bf16 = 128 B + 16 pad
  constexpr int BSTR = 160;          // 64 bf16 = 128 B + 32 pad
  constexpr int ASZ = 128 * ASTR;    // 18 KB
  constexpr int BSZ = 128 * BSTR;    // 20 KB
  __shared__ __align__(16) char sm[2][ASZ + BSZ];  // 76 KB total

  const int tid = threadIdx.x;
  const int w = tid >> 6;
  const int lane = tid & 63;
  const int quad = lane >> 4;
  const int lm = lane & 15;

  const int blk = blockIdx.x;
  const bool is_doc = blk < DBLOCKS;
  const float* X;
  float* Y;
  const int* mask;
  long row0b;
  if (is_doc) {
    X = dh; Y = dv; mask = dmask;
    row0b = (long)blk * 128;
  } else {
    X = qh; Y = qv; mask = qmask;
    row0b = (long)(blk - DBLOCKS) * 128;
  }

  // Wave w stages its own 16 rows (A) / 16 n-rows (B).
  // A: 4 instrs x (4 rows x 256 B contiguous); lane reads 16 B at lane*16.
  const float* gA = X + (row0b + w * 16 + (lane >> 4)) * (long)Hh + (lane & 15) * 4;
  // B: 2 instrs x (8 rows x 128 B contiguous); lane reads 16 B.
  const short* gB = Wt + (w * 16 + (lane >> 3)) * Hh + (lane & 7) * 8;
  // LDS destinations (byte offsets), same (row, granule) as the global reads.
  const int aoff = (w * 16 + (lane >> 4)) * ASTR + (lane & 15) * 8;  // bf16: 8 B/lane
  const int boff = (w * 16 + (lane >> 3)) * BSTR + (lane & 7) * 16;

  f32x4 acc[8];
#pragma unroll
  for (int j = 0; j < 8; ++j) acc[j] = (f32x4){0.f, 0.f, 0.f, 0.f};

  float4 ar[4];
  bf16x8 br[2];
  // preload chunk 0
#pragma unroll
  for (int i = 0; i < 4; ++i) ar[i] = *(const float4*)(gA + i * 4 * Hh);
#pragma unroll
  for (int i = 0; i < 2; ++i) br[i] = *(const bf16x8*)(gB + i * 8 * Hh);

  for (int kk = 0; kk < Hh / 64; ++kk) {
    char* bufA = sm[kk & 1];
    char* bufB = sm[kk & 1] + ASZ;

    // pack + write chunk kk regs -> LDS
#pragma unroll
    for (int i = 0; i < 4; ++i) {
      bf16x4 p;
      p[0] = f2bf(ar[i].x); p[1] = f2bf(ar[i].y);
      p[2] = f2bf(ar[i].z); p[3] = f2bf(ar[i].w);
      *(bf16x4*)(bufA + aoff + i * 4 * ASTR) = p;
    }
#pragma unroll
    for (int i = 0; i < 2; ++i)
      *(bf16x8*)(bufB + boff + i * 8 * BSTR) = br[i];
    __syncthreads();

    // issue next-chunk global loads (overlap with compute below)
    if (kk + 1 < Hh / 64) {
      const long go = (long)(kk + 1) * 64;
#pragma unroll
      for (int i = 0; i < 4; ++i) ar[i] = *(const float4*)(gA + i * 4 * Hh + go);
#pragma unroll
      for (int i = 0; i < 2; ++i) br[i] = *(const bf16x8*)(gB + i * 8 * Hh + go);
    }

    // compute chunk kk: wave tile 16 rows x 128 cols, 2 k-steps of 32
#pragma unroll
    for (int ks = 0; ks < 2; ++ks) {
      bf16x8 fa = *(const bf16x8*)(bufA + (w * 16 + lm) * ASTR + ks * 64 + quad * 16);
#pragma unroll
      for (int j = 0; j < 8; ++j) {
        bf16x8 fb = *(const bf16x8*)(bufB + (j * 16 + lm) * BSTR + ks * 64 + quad * 16);
        acc[j] = __builtin_amdgcn_mfma_f32_16x16x32_bf16(fa, fb, acc[j], 0, 0, 0);
      }
    }
    // NOTE: single barrier per chunk is safe with double buffering:
    // readers of buf[cur]@kk finish before barrier@kk+1; next write to
    // buf[cur] is @kk+2, after that barrier.
  }

  // Epilogue. C/D layout: col = j*16 + lm, row = quad*4 + r (within wave tile).
  const long row0 = row0b + w * 16;
  float bc[8], wsv[8];
#pragma unroll
  for (int j = 0; j < 8; ++j) bc[j] = bcomp[j * 16 + lm];
  if (is_doc) {
#pragma unroll
    for (int j = 0; j < 8; ++j) wsv[j] = wstop[j * 16 + lm];
  }
  const float bs = is_doc ? bstop[0] : 0.f;

#pragma unroll
  for (int r = 0; r < 4; ++r) {
    const long row = row0 + quad * 4 + r;
    float v[8];
#pragma unroll
    for (int j = 0; j < 8; ++j) v[j] = acc[j][r] + bc[j];
    float scale;
    if (is_doc) {
      // importance = relu(d_tok . w_stop + b_stop); the row's 128 cols live
      // on the 16 lanes of this quad -> butterfly sum within the quad.
      float p = 0.f;
#pragma unroll
      for (int j = 0; j < 8; ++j) p += v[j] * wsv[j];
      p += __shfl_xor(p, 1);
      p += __shfl_xor(p, 2);
      p += __shfl_xor(p, 4);
      p += __shfl_xor(p, 8);
      float imp = fmaxf(p + bs, 0.f);
      scale = imp * (float)mask[row];
    } else {
      scale = (float)mask[row];
    }
    float* yr = Y + row * Cc;
#pragma unroll
    for (int j = 0; j < 8; ++j) yr[j * 16 + lm] = v[j] * scale;
  }
}

// Scores: per (chunk of 64 doc tokens, batch): partial max over k per q row.
__global__ __launch_bounds__(256) void k_scores(
    const float* __restrict__ Qv, const float* __restrict__ Dv,
    const int* __restrict__ dmask, float* __restrict__ partial) {
  const int chunk = blockIdx.x;  // 0..7
  const int b = blockIdx.y;
  const int tid = threadIdx.x;
  __shared__ float lq[LQ][Cc + 4];   // +4 keeps 16B align, breaks conflicts
  __shared__ float ldv[64][Cc + 4];
  __shared__ float pm[LQ][16];
  __shared__ int dmsk[64];

  {
    const float4* src = (const float4*)(Qv + (size_t)b * LQ * Cc);
    for (int i = tid; i < LQ * Cc / 4; i += 256) {
      float4 v = src[i];
      int q = i >> 5;
      int c = (i & 31) << 2;
      *(float4*)&lq[q][c] = v;
    }
  }
  const int k0 = chunk * 64;
  {
    const float4* src = (const float4*)(Dv + ((size_t)b * LD + k0) * Cc);
    for (int i = tid; i < 64 * Cc / 4; i += 256) {
      float4 v = src[i];
      int k = i >> 5;
      int c = (i & 31) << 2;
      *(float4*)&ldv[k][c] = v;
    }
  }
  if (tid < 64) dmsk[tid] = dmask[(size_t)b * LD + k0 + tid];
  __syncthreads();

  const int qt = tid & 15;   // q rows qt and qt+16
  const int kt = tid >> 4;   // 4 doc tokens kt*4..+3
  const int kbase = kt * 4;
  float a[2][4];
#pragma unroll
  for (int qi = 0; qi < 2; ++qi)
#pragma unroll
    for (int ki = 0; ki < 4; ++ki) a[qi][ki] = 0.f;

  for (int c = 0; c < Cc; c += 4) {
    float4 q0 = *(float4*)&lq[qt][c];
    float4 q1 = *(float4*)&lq[qt + 16][c];
    float4 d0 = *(float4*)&ldv[kbase + 0][c];
    float4 d1 = *(float4*)&ldv[kbase + 1][c];
    float4 d2 = *(float4*)&ldv[kbase + 2][c];
    float4 d3 = *(float4*)&ldv[kbase + 3][c];
    a[0][0] += q0.x * d0.x + q0.y * d0.y + q0.z * d0.z + q0.w * d0.w;
    a[0][1] += q0.x * d1.x + q0.y * d1.y + q0.z * d1.z + q0.w * d1.w;
    a[0][2] += q0.x * d2.x + q0.y * d2.y + q0.z * d2.z + q0.w * d2.w;
    a[0][3] += q0.x * d3.x + q0.y * d3.y + q0.z * d3.z + q0.w * d3.w;
    a[1][0] += q1.x * d0.x + q1.y * d0.y + q1.z * d0.z + q1.w * d0.w;
    a[1][1] += q1.x * d1.x + q1.y * d1.y + q1.z * d1.z + q1.w * d1.w;
    a[1][2] += q1.x * d2.x + q1.y * d2.y + q1.z * d2.z + q1.w * d2.w;
    a[1][3] += q1.x * d3.x + q1.y * d3.y + q1.z * d3.z + q1.w * d3.w;
  }
  float m0 = -1000.f, m1 = -1000.f;
#pragma unroll
  for (int ki = 0; ki < 4; ++ki) {
    if (dmsk[kbase + ki]) {
      m0 = fmaxf(m0, a[0][ki]);
      m1 = fmaxf(m1, a[1][ki]);
    }
  }
  pm[qt][kt] = m0;
  pm[qt + 16][kt] = m1;
  __syncthreads();
  if (tid < LQ) {
    float mx = pm[tid][0];
#pragma unroll
    for (int t = 1; t < 16; ++t) mx = fmaxf(mx, pm[tid][t]);
    partial[((size_t)b * LQ + tid) * 8 + chunk] = mx;
  }
}

// Finalize: cls dot on raw CLS vectors, max over chunks, masked sum, merge.
__global__ __launch_bounds__(256) void k_final(
    const float* __restrict__ qh, const float* __restrict__ dh,
    const int* __restrict__ qmask, const float* __restrict__ partial,
    const float* __restrict__ merger, float* __restrict__ out) {
  const int b = blockIdx.x;
  const int tid = threadIdx.x;
  __shared__ float red[256];
  __shared__ float clss;
  const float* qc = qh + (size_t)b * LQ * Hh;  // q row 0 = CLS
  const float* dc = dh + (size_t)b * LD * Hh;  // d row 0 = CLS
  float s = 0.f;
  for (int h = tid; h < Hh; h += 256) s += qc[h] * dc[h];
  red[tid] = s;
  __syncthreads();
  for (int off = 128; off > 0; off >>= 1) {
    if (tid < off) red[tid] += red[tid + off];
    __syncthreads();
  }
  if (tid == 0) clss = red[0];
  __syncthreads();
  float t = 0.f;
  if (tid < LQ) {
    const float* pp = partial + ((size_t)b * LQ + tid) * 8;
    float mx = pp[0];
#pragma unroll
    for (int c = 1; c < 8; ++c) mx = fmaxf(mx, pp[c]);
    if (qmask[b * LQ + tid]) t = mx;
  }
  red[tid] = t;
  __syncthreads();
  for (int off = 128; off > 0; off >>= 1) {
    if (tid < off) red[tid] += red[tid + off];
    __syncthreads();
  }
  if (tid == 0) {
    float w = 1.f / (1.f + expf(-merger[0]));
    float cs = clss * w;
    float ts = red[0] * (1.f - w);
    out[b] = cs + ts;        // score
    out[Bb + b] = cs;        // cls_score
    out[2 * Bb + b] = ts;    // term_score
  }
}

extern "C" void kernel_launch(void* const* d_in, const int* in_sizes, int n_in,
                              void* d_out, int out_size, void* d_ws, size_t ws_size,
                              hipStream_t stream) {
  const float* qh  = (const float*)d_in[0];  // (B,LQ,H)
  const float* dh  = (const float*)d_in[1];  // (B,LD,H)
  const int*   qm  = (const int*)d_in[2];    // (B,LQ)
  const int*   dm  = (const int*)d_in[3];    // (B,LD)
  const float* W   = (const float*)d_in[4];  // (H,C)
  const float* bc  = (const float*)d_in[5];  // (C)
  const float* wst = (const float*)d_in[6];  // (C,1)
  const float* bst = (const float*)d_in[7];  // (1)
  const float* mrg = (const float*)d_in[8];  // (1)
  float* out = (float*)d_out;                // 3*B floats

  char* ws = (char*)d_ws;
  short* Wt  = (short*)ws;                                  // 192 KB bf16 W^T
  float* qv  = (float*)(ws + 196608);                       // 2 MB q_vecs
  float* dv  = (float*)(ws + 196608 + 2097152);             // 32 MB d_vecs
  float* prt = (float*)(ws + 196608 + 2097152 + 33554432);  // 128 KB partial max

  k_wt<<<(Hh * Cc) / 256, 256, 0, stream>>>(W, Wt);
  k_proj_all<<<DBLOCKS + QBLOCKS, 512, 0, stream>>>(qh, dh, Wt, bc, qm, dm,
                                                    wst, bst, qv, dv);
  k_scores<<<dim3(8, Bb), 256, 0, stream>>>(qv, dv, dm, prt);
  k_final<<<Bb, 256, 0, stream>>>(qh, dh, qm, prt, mrg, out);
}

// Round 5
// 339.395 us; speedup vs baseline: 1.1736x; 1.0127x over previous
//
#include <hip/hip_runtime.h>
#include <hip/hip_bf16.h>

#define Bb 128
#define LQ 32
#define LD 512
#define Hh 768
#define Cc 128

#define DBLOCKS ((Bb * LD) / 64)   // 1024 doc blocks (64 rows each)
#define QBLOCKS ((Bb * LQ) / 64)   // 64 query blocks

typedef short bf16x8 __attribute__((ext_vector_type(8)));
typedef short bf16x4 __attribute__((ext_vector_type(4)));
typedef float f32x4 __attribute__((ext_vector_type(4)));

__device__ __forceinline__ short f2bf(float f) {
  union { float f; unsigned u; } v;
  v.f = f;
  unsigned u = v.u + (0x7FFFu + ((v.u >> 16) & 1u));  // RNE
  return (short)(u >> 16);
}

// K0: W (H,C) fp32 -> Wt (C,H) bf16 (transposed so B-chunks are row-contiguous)
__global__ __launch_bounds__(256) void k_wt(const float* __restrict__ W,
                                            short* __restrict__ Wt) {
  int idx = blockIdx.x * 256 + threadIdx.x;  // grid covers H*C exactly
  int h = idx >> 7;   // / 128
  int c = idx & 127;
  Wt[c * Hh + h] = f2bf(W[idx]);
}

// Merged projection GEMM (query+doc): Y = X @ W + b_comp, fused mask
// (+ importance relu-dot for docs).
// 256 thr = 4 waves; block tile 64 rows x 128 cols; BK=64.
// Single-buffered LDS (29 KB) -> 4+ blocks co-resident per CU; grid 1088
// gives ~4.25 blocks/CU so phase-staggered blocks keep the memory system
// busy between barriers (R4's 2-block dbuf ran at only ~40% memory duty).
// m97-style 2-barrier K-loop; next-chunk global loads issue right after the
// second barrier with a full compute phase to land.
__global__ __launch_bounds__(256, 4) void k_proj_all(
    const float* __restrict__ qh, const float* __restrict__ dh,
    const short* __restrict__ Wt, const float* __restrict__ bcomp,
    const int* __restrict__ qmask, const int* __restrict__ dmask,
    const float* __restrict__ wstop, const float* __restrict__ bstop,
    float* __restrict__ qv, float* __restrict__ dv) {
  constexpr int ASTR = 144;          // 64 bf16 = 128 B + 16 pad
  constexpr int BSTR = 160;          // 64 bf16 = 128 B + 32 pad
  constexpr int ASZ = 64 * ASTR;     // 9 KB
  constexpr int BSZ = 128 * BSTR;    // 20 KB
  __shared__ __align__(16) char sm[ASZ + BSZ];  // 29 KB, single buffer

  const int tid = threadIdx.x;
  const int w = tid >> 6;
  const int lane = tid & 63;
  const int quad = lane >> 4;
  const int lm = lane & 15;

  const int blk = blockIdx.x;
  const bool is_doc = blk < DBLOCKS;
  const float* X;
  float* Y;
  const int* mask;
  long row0b;
  if (is_doc) {
    X = dh; Y = dv; mask = dmask;
    row0b = (long)blk * 64;
  } else {
    X = qh; Y = qv; mask = qmask;
    row0b = (long)(blk - DBLOCKS) * 64;
  }

  // Wave w stages its 16 A-rows and 32 B-n-rows.
  // A: 4 instrs x (4 rows x 256 B contiguous); lane reads 16 B.
  const float* gA = X + (row0b + w * 16 + (lane >> 4)) * (long)Hh + (lane & 15) * 4;
  // B: 4 instrs x (8 rows x 128 B contiguous); lane reads 16 B.
  const short* gB = Wt + (w * 32 + (lane >> 3)) * Hh + (lane & 7) * 8;
  // LDS destinations (byte offsets), same (row, granule) as the global reads.
  const int aoff = (w * 16 + (lane >> 4)) * ASTR + (lane & 15) * 8;  // bf16: 8 B
  const int boff = (w * 32 + (lane >> 3)) * BSTR + (lane & 7) * 16;

  char* bufA = sm;
  char* bufB = sm + ASZ;

  f32x4 acc[8];
#pragma unroll
  for (int j = 0; j < 8; ++j) acc[j] = (f32x4){0.f, 0.f, 0.f, 0.f};

  float4 ar[4];
  bf16x8 br[4];
  // preload chunk 0
#pragma unroll
  for (int i = 0; i < 4; ++i) ar[i] = *(const float4*)(gA + i * 4 * Hh);
#pragma unroll
  for (int i = 0; i < 4; ++i) br[i] = *(const bf16x8*)(gB + i * 8 * Hh);

  for (int kk = 0; kk < Hh / 64; ++kk) {
    __syncthreads();  // previous chunk's readers done
    // pack + write chunk kk regs -> LDS
#pragma unroll
    for (int i = 0; i < 4; ++i) {
      bf16x4 p;
      p[0] = f2bf(ar[i].x); p[1] = f2bf(ar[i].y);
      p[2] = f2bf(ar[i].z); p[3] = f2bf(ar[i].w);
      *(bf16x4*)(bufA + aoff + i * 4 * ASTR) = p;
    }
#pragma unroll
    for (int i = 0; i < 4; ++i)
      *(bf16x8*)(bufB + boff + i * 8 * BSTR) = br[i];
    __syncthreads();  // LDS tile visible

    // issue next-chunk global loads; they have the whole compute phase to land
    {
      const long go = (kk + 1 < Hh / 64) ? (long)(kk + 1) * 64 : 0;
#pragma unroll
      for (int i = 0; i < 4; ++i) ar[i] = *(const float4*)(gA + i * 4 * Hh + go);
#pragma unroll
      for (int i = 0; i < 4; ++i) br[i] = *(const bf16x8*)(gB + i * 8 * Hh + go);
    }

    // compute chunk kk: wave tile 16 rows x 128 cols, 2 k-steps of 32
#pragma unroll
    for (int ks = 0; ks < 2; ++ks) {
      bf16x8 fa = *(const bf16x8*)(bufA + (w * 16 + lm) * ASTR + ks * 64 + quad * 16);
#pragma unroll
      for (int j = 0; j < 8; ++j) {
        bf16x8 fb = *(const bf16x8*)(bufB + (j * 16 + lm) * BSTR + ks * 64 + quad * 16);
        acc[j] = __builtin_amdgcn_mfma_f32_16x16x32_bf16(fa, fb, acc[j], 0, 0, 0);
      }
    }
  }

  // Epilogue. C/D layout: col = j*16 + lm, row = quad*4 + r (within wave tile).
  const long row0 = row0b + w * 16;
  float bc[8], wsv[8];
#pragma unroll
  for (int j = 0; j < 8; ++j) bc[j] = bcomp[j * 16 + lm];
  if (is_doc) {
#pragma unroll
    for (int j = 0; j < 8; ++j) wsv[j] = wstop[j * 16 + lm];
  }
  const float bs = is_doc ? bstop[0] : 0.f;

#pragma unroll
  for (int r = 0; r < 4; ++r) {
    const long row = row0 + quad * 4 + r;
    float v[8];
#pragma unroll
    for (int j = 0; j < 8; ++j) v[j] = acc[j][r] + bc[j];
    float scale;
    if (is_doc) {
      // importance = relu(d_tok . w_stop + b_stop); the row's 128 cols live
      // on the 16 lanes of this quad -> butterfly sum within the quad.
      float p = 0.f;
#pragma unroll
      for (int j = 0; j < 8; ++j) p += v[j] * wsv[j];
      p += __shfl_xor(p, 1);
      p += __shfl_xor(p, 2);
      p += __shfl_xor(p, 4);
      p += __shfl_xor(p, 8);
      float imp = fmaxf(p + bs, 0.f);
      scale = imp * (float)mask[row];
    } else {
      scale = (float)mask[row];
    }
    float* yr = Y + row * Cc;
#pragma unroll
    for (int j = 0; j < 8; ++j) yr[j * 16 + lm] = v[j] * scale;
  }
}

// Scores: per (chunk of 64 doc tokens, batch): partial max over k per q row.
__global__ __launch_bounds__(256) void k_scores(
    const float* __restrict__ Qv, const float* __restrict__ Dv,
    const int* __restrict__ dmask, float* __restrict__ partial) {
  const int chunk = blockIdx.x;  // 0..7
  const int b = blockIdx.y;
  const int tid = threadIdx.x;
  __shared__ float lq[LQ][Cc + 4];   // +4 keeps 16B align, breaks conflicts
  __shared__ float ldv[64][Cc + 4];
  __shared__ float pm[LQ][16];
  __shared__ int dmsk[64];

  {
    const float4* src = (const float4*)(Qv + (size_t)b * LQ * Cc);
    for (int i = tid; i < LQ * Cc / 4; i += 256) {
      float4 v = src[i];
      int q = i >> 5;
      int c = (i & 31) << 2;
      *(float4*)&lq[q][c] = v;
    }
  }
  const int k0 = chunk * 64;
  {
    const float4* src = (const float4*)(Dv + ((size_t)b * LD + k0) * Cc);
    for (int i = tid; i < 64 * Cc / 4; i += 256) {
      float4 v = src[i];
      int k = i >> 5;
      int c = (i & 31) << 2;
      *(float4*)&ldv[k][c] = v;
    }
  }
  if (tid < 64) dmsk[tid] = dmask[(size_t)b * LD + k0 + tid];
  __syncthreads();

  const int qt = tid & 15;   // q rows qt and qt+16
  const int kt = tid >> 4;   // 4 doc tokens kt*4..+3
  const int kbase = kt * 4;
  float a[2][4];
#pragma unroll
  for (int qi = 0; qi < 2; ++qi)
#pragma unroll
    for (int ki = 0; ki < 4; ++ki) a[qi][ki] = 0.f;

  for (int c = 0; c < Cc; c += 4) {
    float4 q0 = *(float4*)&lq[qt][c];
    float4 q1 = *(float4*)&lq[qt + 16][c];
    float4 d0 = *(float4*)&ldv[kbase + 0][c];
    float4 d1 = *(float4*)&ldv[kbase + 1][c];
    float4 d2 = *(float4*)&ldv[kbase + 2][c];
    float4 d3 = *(float4*)&ldv[kbase + 3][c];
    a[0][0] += q0.x * d0.x + q0.y * d0.y + q0.z * d0.z + q0.w * d0.w;
    a[0][1] += q0.x * d1.x + q0.y * d1.y + q0.z * d1.z + q0.w * d1.w;
    a[0][2] += q0.x * d2.x + q0.y * d2.y + q0.z * d2.z + q0.w * d2.w;
    a[0][3] += q0.x * d3.x + q0.y * d3.y + q0.z * d3.z + q0.w * d3.w;
    a[1][0] += q1.x * d0.x + q1.y * d0.y + q1.z * d0.z + q1.w * d0.w;
    a[1][1] += q1.x * d1.x + q1.y * d1.y + q1.z * d1.z + q1.w * d1.w;
    a[1][2] += q1.x * d2.x + q1.y * d2.y + q1.z * d2.z + q1.w * d2.w;
    a[1][3] += q1.x * d3.x + q1.y * d3.y + q1.z * d3.z + q1.w * d3.w;
  }
  float m0 = -1000.f, m1 = -1000.f;
#pragma unroll
  for (int ki = 0; ki < 4; ++ki) {
    if (dmsk[kbase + ki]) {
      m0 = fmaxf(m0, a[0][ki]);
      m1 = fmaxf(m1, a[1][ki]);
    }
  }
  pm[qt][kt] = m0;
  pm[qt + 16][kt] = m1;
  __syncthreads();
  if (tid < LQ) {
    float mx = pm[tid][0];
#pragma unroll
    for (int t = 1; t < 16; ++t) mx = fmaxf(mx, pm[tid][t]);
    partial[((size_t)b * LQ + tid) * 8 + chunk] = mx;
  }
}

// Finalize: cls dot on raw CLS vectors, max over chunks, masked sum, merge.
__global__ __launch_bounds__(256) void k_final(
    const float* __restrict__ qh, const float* __restrict__ dh,
    const int* __restrict__ qmask, const float* __restrict__ partial,
    const float* __restrict__ merger, float* __restrict__ out) {
  const int b = blockIdx.x;
  const int tid = threadIdx.x;
  __shared__ float red[256];
  __shared__ float clss;
  const float* qc = qh + (size_t)b * LQ * Hh;  // q row 0 = CLS
  const float* dc = dh + (size_t)b * LD * Hh;  // d row 0 = CLS
  float s = 0.f;
  for (int h = tid; h < Hh; h += 256) s += qc[h] * dc[h];
  red[tid] = s;
  __syncthreads();
  for (int off = 128; off > 0; off >>= 1) {
    if (tid < off) red[tid] += red[tid + off];
    __syncthreads();
  }
  if (tid == 0) clss = red[0];
  __syncthreads();
  float t = 0.f;
  if (tid < LQ) {
    const float* pp = partial + ((size_t)b * LQ + tid) * 8;
    float mx = pp[0];
#pragma unroll
    for (int c = 1; c < 8; ++c) mx = fmaxf(mx, pp[c]);
    if (qmask[b * LQ + tid]) t = mx;
  }
  red[tid] = t;
  __syncthreads();
  for (int off = 128; off > 0; off >>= 1) {
    if (tid < off) red[tid] += red[tid + off];
    __syncthreads();
  }
  if (tid == 0) {
    float w = 1.f / (1.f + expf(-merger[0]));
    float cs = clss * w;
    float ts = red[0] * (1.f - w);
    out[b] = cs + ts;        // score
    out[Bb + b] = cs;        // cls_score
    out[2 * Bb + b] = ts;    // term_score
  }
}

extern "C" void kernel_launch(void* const* d_in, const int* in_sizes, int n_in,
                              void* d_out, int out_size, void* d_ws, size_t ws_size,
                              hipStream_t stream) {
  const float* qh  = (const float*)d_in[0];  // (B,LQ,H)
  const float* dh  = (const float*)d_in[1];  // (B,LD,H)
  const int*   qm  = (const int*)d_in[2];    // (B,LQ)
  const int*   dm  = (const int*)d_in[3];    // (B,LD)
  const float* W   = (const float*)d_in[4];  // (H,C)
  const float* bc  = (const float*)d_in[5];  // (C)
  const float* wst = (const float*)d_in[6];  // (C,1)
  const float* bst = (const float*)d_in[7];  // (1)
  const float* mrg = (const float*)d_in[8];  // (1)
  float* out = (float*)d_out;                // 3*B floats

  char* ws = (char*)d_ws;
  short* Wt  = (short*)ws;                                  // 192 KB bf16 W^T
  float* qv  = (float*)(ws + 196608);                       // 2 MB q_vecs
  float* dv  = (float*)(ws + 196608 + 2097152);             // 32 MB d_vecs
  float* prt = (float*)(ws + 196608 + 2097152 + 33554432);  // 128 KB partial max

  k_wt<<<(Hh * Cc) / 256, 256, 0, stream>>>(W, Wt);
  k_proj_all<<<DBLOCKS + QBLOCKS, 256, 0, stream>>>(qh, dh, Wt, bc, qm, dm,
                                                    wst, bst, qv, dv);
  k_scores<<<dim3(8, Bb), 256, 0, stream>>>(qv, dv, dm, prt);
  k_final<<<Bb, 256, 0, stream>>>(qh, dh, qm, prt, mrg, out);
}